// Round 2
// 80.934 us; speedup vs baseline: 1.2283x; 1.2283x over previous
//
#include <hip/hip_runtime.h>
#include <math.h>

typedef float f32x4 __attribute__((ext_vector_type(4)));
typedef _Float16 f16;
typedef f16 f16x8 __attribute__((ext_vector_type(8)));
typedef unsigned int u32;
typedef u32 u32x2 __attribute__((ext_vector_type(2)));

#define BB 4096
#define TT 200
#define DD 32
#define H1 80
#define H2 40
#define SLAB_W 104   // f16 per slab row: 96 used + 8 pad -> 208B stride (13x16B), even bank spread

// packed tables (f32) + W2 fragment tables (f16 hi/lo), coarse device globals
__device__ __align__(16) float g_BCj[DD * H1];   // (B-C)[k][j]
__device__ __align__(16) float g_Dj [DD * H1];   // D[k][j]
__device__ __align__(16) float g_ACj[DD * H1];   // (A+C)[k][j]
__device__ __align__(16) f16 g_w2h[9 * 64 * 8];  // [kt*3+n][lane][e]
__device__ __align__(16) f16 g_w2l[9 * 64 * 8];

__device__ __forceinline__ float fast_sigmoid(float x) {
    return __builtin_amdgcn_rcpf(1.f + __expf(-x));
}

__global__ void pack_kernel(const float* __restrict__ W1, const float* __restrict__ W2) {
    int idx = blockIdx.x * 256 + threadIdx.x;
    if (idx < DD * H1) {
        int kk = idx / H1, j = idx % H1;
        g_BCj[idx] = W1[(32 + kk) * H1 + j] - W1[(64 + kk) * H1 + j];
        g_Dj [idx] = W1[(96 + kk) * H1 + j];
        g_ACj[idx] = W1[kk * H1 + j] + W1[(64 + kk) * H1 + j];
        return;
    }
    idx -= DD * H1;
    if (idx < 9 * 64 * 8) {                       // W2 fragments, padded K=96 N=48
        int e = idx & 7, l = (idx >> 3) & 63, g = idx >> 9;
        int kt = g / 3, n = g % 3;
        int j   = kt * 32 + (l >> 4) * 8 + e;     // K index (H1 dim)
        int col = n * 16 + (l & 15);              // N index (H2 dim)
        float v = (j < H1 && col < H2) ? W2[j * H2 + col] : 0.f;
        f16 hi = (f16)v;
        g_w2h[idx] = hi;
        g_w2l[idx] = (f16)(v - (float)hi);
    }
}

__global__ __launch_bounds__(256) void din_mfma(
    const float* __restrict__ q, const float* __restrict__ k, const int* __restrict__ mask,
    const float* __restrict__ Wq, const float* __restrict__ bq, const float* __restrict__ alpha,
    const float* __restrict__ b1, const float* __restrict__ b2, const float* __restrict__ Wf,
    float* __restrict__ out)
{
    const int b   = blockIdx.x;
    const int tid = threadIdx.x;
    const int wid = tid >> 6, l = tid & 63;
    const int l15 = l & 15, lg4 = l >> 4;

    __shared__ __align__(16) f16   slab[4][16][SLAB_W];  // per-wave sg (f16 hi only)
    __shared__ __align__(16) float qp_s[DD];
    __shared__ __align__(16) float u_s[H1];
    __shared__ float lgt[208];
    __shared__ float red[8];

    // ---- phase 0a: qp = prelu(q[b] @ Wq + bq) ----
    if (tid < DD) {
        const float* qr = q + (size_t)b * DD;
        float acc = bq[tid];
        #pragma unroll
        for (int e = 0; e < DD; ++e) acc += qr[e] * Wq[e * DD + tid];
        float a = alpha[tid];
        qp_s[tid] = acc >= 0.f ? acc : a * acc;
    }
    // zero full slab once (covers the j=80..95 pad region read by L2 kt=2)
    {
        u32* sz = (u32*)slab;                    // 4*16*104 f16 = 3328 u32 = 13*256
        #pragma unroll
        for (int i = 0; i < 13; ++i) sz[i * 256 + tid] = 0u;
    }
    __syncthreads();

    // ---- phase 0b: u[j] = b1[j] + qp.(A+C)[:,j] ; per-lane L1 A-frags (W1') hi/lo ----
    if (tid < H1) {
        float acc = b1[tid];
        #pragma unroll
        for (int d = 0; d < DD; ++d) acc += qp_s[d] * g_ACj[d * H1 + tid];
        u_s[tid] = acc;
    }
    f16x8 Bh[5], Bl[5];                          // A-operand for transposed L1: [j=n*16+l15][d=lg4*8+e]
    #pragma unroll
    for (int n = 0; n < 5; ++n) {
        #pragma unroll
        for (int e = 0; e < 8; ++e) {
            int kidx = lg4 * 8 + e;
            int j = n * 16 + l15;
            float v = g_BCj[kidx * H1 + j] + qp_s[kidx] * g_Dj[kidx * H1 + j];
            f16 hi = (f16)v;
            Bh[n][e] = hi;
            Bl[n][e] = (f16)(v - (float)hi);
        }
    }
    // W2 fragments (lane-contiguous 16B loads)
    f16x8 W2h[9], W2l[9];
    #pragma unroll
    for (int g = 0; g < 9; ++g) {
        W2h[g] = *(const f16x8*)(g_w2h + (g * 64 + l) * 8);
        W2l[g] = *(const f16x8*)(g_w2l + (g * 64 + l) * 8);
    }
    // per-lane b2/Wf (col = n*16+l15), straight from global (L2-cached)
    float blr[3], wlr[3];
    #pragma unroll
    for (int n = 0; n < 3; ++n) {
        int col = n * 16 + l15;
        blr[n] = col < H2 ? b2[col] : 0.f;
        wlr[n] = col < H2 ? Wf[col] : 0.f;
    }
    __syncthreads();

    // ---- main loop: per m-tile, L1' GEMM (D[j][t]) -> sigmoid -> f16 slab -> L2 GEMM -> logits ----
    const float* kb = k + (size_t)b * (TT * DD);
    f16 (*ws)[SLAB_W] = slab[wid];

    // prefetch first tile's k rows
    f32x4 x0, x1;
    {
        int t = wid * 16 + l15; if (t > TT - 1) t = TT - 1;
        const f32x4* kr = (const f32x4*)(kb + t * DD + lg4 * 8);
        x0 = kr[0]; x1 = kr[1];
    }

    for (int m = wid; m < 13; m += 4) {
        // B-operand (k rows, col t=l15, k-slice lg4*8..+8), f16 hi/lo
        f16x8 Ah, Al;
        #pragma unroll
        for (int e = 0; e < 4; ++e) {
            f16 h0 = (f16)x0[e]; Ah[e]     = h0; Al[e]     = (f16)(x0[e] - (float)h0);
            f16 h1 = (f16)x1[e]; Ah[e + 4] = h1; Al[e + 4] = (f16)(x1[e] - (float)h1);
        }
        // software-prefetch next m-tile's k rows (hides L2/L3 latency under MFMA phase)
        int mn = m + 4;
        if (mn < 13) {
            int tn = mn * 16 + l15; if (tn > TT - 1) tn = TT - 1;
            const f32x4* kr = (const f32x4*)(kb + tn * DD + lg4 * 8);
            x0 = kr[0]; x1 = kr[1];
        }

        // L1' (transposed): acc[r] = u[j0+r] + W1'[j0+r][:] . k[t=l15][:]
        #pragma unroll
        for (int n = 0; n < 5; ++n) {
            int j0 = n * 16 + lg4 * 4;
            f32x4 acc = *(const f32x4*)(u_s + j0);      // bias folded into accumulator init
            acc = __builtin_amdgcn_mfma_f32_16x16x32_f16(Bh[n], Ah, acc, 0, 0, 0);
            acc = __builtin_amdgcn_mfma_f32_16x16x32_f16(Bl[n], Ah, acc, 0, 0, 0);
            acc = __builtin_amdgcn_mfma_f32_16x16x32_f16(Bh[n], Al, acc, 0, 0, 0);
            // lane owns 4 consecutive j at row t=l15 -> pack + single ds_write_b64
            auto p01 = __builtin_amdgcn_cvt_pkrtz(fast_sigmoid(acc[0]), fast_sigmoid(acc[1]));
            auto p23 = __builtin_amdgcn_cvt_pkrtz(fast_sigmoid(acc[2]), fast_sigmoid(acc[3]));
            u32x2 w;
            w[0] = __builtin_bit_cast(u32, p01);
            w[1] = __builtin_bit_cast(u32, p23);
            *(u32x2*)(&ws[l15][j0]) = w;
        }

        // L2: A = sg[t=l15][j-slice] direct f16x8 from slab (no unpack), B = W2 hi/lo
        f32x4 a0 = {0.f,0.f,0.f,0.f}, a1 = {0.f,0.f,0.f,0.f}, a2 = {0.f,0.f,0.f,0.f};
        #pragma unroll
        for (int kt = 0; kt < 3; ++kt) {
            f16x8 sh = *(const f16x8*)(&ws[l15][kt * 32 + lg4 * 8]);
            a0 = __builtin_amdgcn_mfma_f32_16x16x32_f16(sh, W2h[kt * 3 + 0], a0, 0, 0, 0);
            a0 = __builtin_amdgcn_mfma_f32_16x16x32_f16(sh, W2l[kt * 3 + 0], a0, 0, 0, 0);
            a1 = __builtin_amdgcn_mfma_f32_16x16x32_f16(sh, W2h[kt * 3 + 1], a1, 0, 0, 0);
            a1 = __builtin_amdgcn_mfma_f32_16x16x32_f16(sh, W2l[kt * 3 + 1], a1, 0, 0, 0);
            a2 = __builtin_amdgcn_mfma_f32_16x16x32_f16(sh, W2h[kt * 3 + 2], a2, 0, 0, 0);
            a2 = __builtin_amdgcn_mfma_f32_16x16x32_f16(sh, W2l[kt * 3 + 2], a2, 0, 0, 0);
        }
        float p0 = 0.f, p1 = 0.f, p2 = 0.f, p3 = 0.f;
        #pragma unroll
        for (int n = 0; n < 3; ++n) {
            f32x4 av = (n == 0) ? a0 : (n == 1) ? a1 : a2;
            p0 += wlr[n] * fast_sigmoid(av[0] + blr[n]);
            p1 += wlr[n] * fast_sigmoid(av[1] + blr[n]);
            p2 += wlr[n] * fast_sigmoid(av[2] + blr[n]);
            p3 += wlr[n] * fast_sigmoid(av[3] + blr[n]);
        }
        #pragma unroll
        for (int off = 1; off < 16; off <<= 1) {
            p0 += __shfl_xor(p0, off);
            p1 += __shfl_xor(p1, off);
            p2 += __shfl_xor(p2, off);
            p3 += __shfl_xor(p3, off);
        }
        if (l15 == 0) {
            int tb = m * 16 + lg4 * 4;
            lgt[tb + 0] = p0; lgt[tb + 1] = p1; lgt[tb + 2] = p2; lgt[tb + 3] = p3;
        }
    }
    __syncthreads();

    // ---- phase 3: masked softmax over t<200 (bf dropped: shift-invariant) ----
    float logit;
    if (tid < TT) {
        logit = lgt[tid];
        if (mask[(size_t)b * TT + tid] == 0) logit = -4294967295.0f;   // -2^32+1
    } else {
        logit = -8589934590.0f;
    }
    float mx = logit;
    #pragma unroll
    for (int off = 32; off; off >>= 1) mx = fmaxf(mx, __shfl_xor(mx, off));
    if ((tid & 63) == 0) red[tid >> 6] = mx;
    __syncthreads();
    float M = fmaxf(fmaxf(red[0], red[1]), fmaxf(red[2], red[3]));

    float e = (tid < TT) ? __expf(logit - M) : 0.f;
    float ssum = e;
    #pragma unroll
    for (int off = 32; off; off >>= 1) ssum += __shfl_xor(ssum, off);
    if ((tid & 63) == 0) red[4 + (tid >> 6)] = ssum;
    __syncthreads();
    float S = (red[4] + red[5]) + (red[6] + red[7]);

    if (tid < TT) out[(size_t)b * TT + tid] = e / S;
}

extern "C" void kernel_launch(void* const* d_in, const int* in_sizes, int n_in,
                              void* d_out, int out_size, void* d_ws, size_t ws_size,
                              hipStream_t stream) {
    const float* q     = (const float*)d_in[0];
    const float* k     = (const float*)d_in[1];
    // d_in[2] = v : unused by the reference output
    const int*   mask  = (const int*)d_in[3];
    const float* Wq    = (const float*)d_in[4];
    const float* bq    = (const float*)d_in[5];
    const float* alpha = (const float*)d_in[6];
    const float* W1    = (const float*)d_in[7];
    const float* b1    = (const float*)d_in[8];
    const float* W2    = (const float*)d_in[9];
    const float* b2    = (const float*)d_in[10];
    const float* Wf    = (const float*)d_in[11];
    // d_in[12] = bf : dropped (softmax is shift-invariant, incl. all-masked rows)
    float* out = (float*)d_out;

    hipLaunchKernelGGL(pack_kernel, dim3((DD * H1 + 9 * 64 * 8 + 255) / 256), dim3(256),
                       0, stream, W1, W2);
    hipLaunchKernelGGL(din_mfma, dim3(BB), dim3(256), 0, stream,
                       q, k, mask, Wq, bq, alpha, b1, b2, Wf, out);
}

// Round 3
// 62.125 us; speedup vs baseline: 1.6001x; 1.3028x over previous
//
#include <hip/hip_runtime.h>
#include <math.h>

typedef float f32x4 __attribute__((ext_vector_type(4)));
typedef _Float16 f16;
typedef f16 f16x8 __attribute__((ext_vector_type(8)));
typedef unsigned int u32;
typedef u32 u32x2 __attribute__((ext_vector_type(2)));

#define BB 4096
#define TT 200
#define DD 32
#define H1 80
#define H2 40
#define SLAB_W 104   // f16 per slab row: 96 used + 8 pad -> 208B stride, even bank spread

// packed tables (f32) + W2 fragment tables (f16 hi/lo), coarse device globals
__device__ __align__(16) float g_BCj[DD * H1];   // (B-C)[k][j]
__device__ __align__(16) float g_Dj [DD * H1];   // D[k][j]
__device__ __align__(16) float g_ACj[DD * H1];   // (A+C)[k][j]
__device__ __align__(16) f16 g_w2h[9 * 64 * 8];  // [kt*3+n][lane][e]
__device__ __align__(16) f16 g_w2l[9 * 64 * 8];

__device__ __forceinline__ float fast_sigmoid(float x) {
    return __builtin_amdgcn_rcpf(1.f + __expf(-x));
}

__global__ void pack_kernel(const float* __restrict__ W1, const float* __restrict__ W2) {
    int idx = blockIdx.x * 256 + threadIdx.x;
    if (idx < DD * H1) {
        int kk = idx / H1, j = idx % H1;
        g_BCj[idx] = W1[(32 + kk) * H1 + j] - W1[(64 + kk) * H1 + j];
        g_Dj [idx] = W1[(96 + kk) * H1 + j];
        g_ACj[idx] = W1[kk * H1 + j] + W1[(64 + kk) * H1 + j];
        return;
    }
    idx -= DD * H1;
    if (idx < 9 * 64 * 8) {                       // W2 fragments, padded K=96 N=48
        int e = idx & 7, l = (idx >> 3) & 63, g = idx >> 9;
        int kt = g / 3, n = g % 3;
        int j   = kt * 32 + (l >> 4) * 8 + e;     // K index (H1 dim)
        int col = n * 16 + (l & 15);              // N index (H2 dim)
        float v = (j < H1 && col < H2) ? W2[j * H2 + col] : 0.f;
        f16 hi = (f16)v;
        g_w2h[idx] = hi;
        g_w2l[idx] = (f16)(v - (float)hi);
    }
}

// one batch-row per WAVE; waves fully independent after one staging barrier
__global__ __launch_bounds__(256) void din_mfma(
    const float* __restrict__ q, const float* __restrict__ k, const int* __restrict__ mask,
    const float* __restrict__ Wq, const float* __restrict__ bq, const float* __restrict__ alpha,
    const float* __restrict__ b1, const float* __restrict__ b2, const float* __restrict__ Wf,
    float* __restrict__ out)
{
    const int tid = threadIdx.x;
    const int wid = tid >> 6, l = tid & 63;
    const int l15 = l & 15, lg4 = l >> 4;
    const int b   = (blockIdx.x << 2) | wid;      // this wave's batch row

    __shared__ __align__(16) f16   slab[4][16][SLAB_W];  // per-wave sg (f16 hi only)
    __shared__ __align__(16) f16   w2l_s[9 * 64 * 8];    // W2 lo fragments (block-shared)
    __shared__ __align__(16) float qp_s[4][DD];
    __shared__ __align__(16) float u_s[4][H1];
    __shared__ __align__(16) float lgt[4][208];

    // ---- stage W2l -> LDS (block-wide; only cross-wave dependency) ----
    {
        const u32* src = (const u32*)g_w2l;       // 2304 u32 = 9 * 256
        u32* dst = (u32*)w2l_s;
        #pragma unroll
        for (int i = 0; i < 9; ++i) dst[i * 256 + tid] = src[i * 256 + tid];
    }

    // ---- phase 0a (per wave): qp = prelu(q[b] @ Wq + bq) ----
    if (l < DD) {
        const float* qr = q + (size_t)b * DD;
        float acc = bq[l];
        #pragma unroll
        for (int e = 0; e < DD; ++e) acc += qr[e] * Wq[e * DD + l];
        float a = alpha[l];
        qp_s[wid][l] = acc >= 0.f ? acc : a * acc;
    }
    // zero this wave's slab pad columns j=80..95 (read by L2 kt=2)
    {
        u32* wsz = (u32*)slab[wid];               // 52 u32 per row
        #pragma unroll
        for (int i = 0; i < 2; ++i) {
            int idx = i * 64 + l;                 // 0..127 = 16 rows x 8 u32
            wsz[(idx >> 3) * 52 + 40 + (idx & 7)] = 0u;
        }
    }

    // ---- phase 0b (per wave): u[j] = b1[j] + qp.(A+C)[:,j] ----
    #pragma unroll
    for (int i = 0; i < 2; ++i) {
        int c = i * 64 + l;
        if (c < H1) {
            float acc = b1[c];
            #pragma unroll
            for (int d = 0; d < DD; ++d) acc += qp_s[wid][d] * g_ACj[d * H1 + c];
            u_s[wid][c] = acc;
        }
    }
    // L1 A-operand frags (W1'): [j=n*16+l15][d=lg4*8+e], f16 hi/lo
    f16x8 Bh[5], Bl[5];
    #pragma unroll
    for (int n = 0; n < 5; ++n) {
        #pragma unroll
        for (int e = 0; e < 8; ++e) {
            int kidx = lg4 * 8 + e;
            int j = n * 16 + l15;
            float v = g_BCj[kidx * H1 + j] + qp_s[wid][kidx] * g_Dj[kidx * H1 + j];
            f16 hi = (f16)v;
            Bh[n][e] = hi;
            Bl[n][e] = (f16)(v - (float)hi);
        }
    }
    // W2 hi fragments stay in registers (lane-contiguous 16B loads)
    f16x8 W2h[9];
    #pragma unroll
    for (int g = 0; g < 9; ++g) W2h[g] = *(const f16x8*)(g_w2h + (g * 64 + l) * 8);
    // per-lane b2/Wf (col = n*16+l15)
    float blr[3], wlr[3];
    #pragma unroll
    for (int n = 0; n < 3; ++n) {
        int col = n * 16 + l15;
        blr[n] = col < H2 ? b2[col] : 0.f;
        wlr[n] = col < H2 ? Wf[col] : 0.f;
    }

    __syncthreads();   // only barrier: w2l_s visible to all waves

    // ---- main loop: 13 m-tiles per wave, no barriers ----
    const float* kb = k + (size_t)b * (TT * DD);
    f16 (*ws)[SLAB_W] = slab[wid];
    float* lg = lgt[wid];

    f32x4 x0, x1;
    {
        const f32x4* kr = (const f32x4*)(kb + l15 * DD + lg4 * 8);
        x0 = kr[0]; x1 = kr[1];
    }

    for (int m = 0; m < 13; ++m) {
        // B-operand (k rows, col t=l15, k-slice lg4*8..+8), f16 hi/lo
        f16x8 Ah, Al;
        #pragma unroll
        for (int e = 0; e < 4; ++e) {
            f16 h0 = (f16)x0[e]; Ah[e]     = h0; Al[e]     = (f16)(x0[e] - (float)h0);
            f16 h1 = (f16)x1[e]; Ah[e + 4] = h1; Al[e + 4] = (f16)(x1[e] - (float)h1);
        }
        // prefetch next m-tile's k rows
        if (m < 12) {
            int tn = (m + 1) * 16 + l15; if (tn > TT - 1) tn = TT - 1;
            const f32x4* kr = (const f32x4*)(kb + tn * DD + lg4 * 8);
            x0 = kr[0]; x1 = kr[1];
        }

        // L1' (transposed): acc[r] = u[j0+r] + W1'[j0+r][:] . k[t=l15][:]
        #pragma unroll
        for (int n = 0; n < 5; ++n) {
            int j0 = n * 16 + lg4 * 4;
            f32x4 acc = *(const f32x4*)(&u_s[wid][j0]);   // bias folded into acc init
            acc = __builtin_amdgcn_mfma_f32_16x16x32_f16(Bh[n], Ah, acc, 0, 0, 0);
            acc = __builtin_amdgcn_mfma_f32_16x16x32_f16(Bl[n], Ah, acc, 0, 0, 0);
            acc = __builtin_amdgcn_mfma_f32_16x16x32_f16(Bh[n], Al, acc, 0, 0, 0);
            auto p01 = __builtin_amdgcn_cvt_pkrtz(fast_sigmoid(acc[0]), fast_sigmoid(acc[1]));
            auto p23 = __builtin_amdgcn_cvt_pkrtz(fast_sigmoid(acc[2]), fast_sigmoid(acc[3]));
            u32x2 w;
            w[0] = __builtin_bit_cast(u32, p01);
            w[1] = __builtin_bit_cast(u32, p23);
            *(u32x2*)(&ws[l15][j0]) = w;
        }

        // L2: A = sg[t=l15][j-slice] from slab, B = W2h (regs) + W2l (LDS)
        f32x4 a0 = {0.f,0.f,0.f,0.f}, a1 = {0.f,0.f,0.f,0.f}, a2 = {0.f,0.f,0.f,0.f};
        #pragma unroll
        for (int kt = 0; kt < 3; ++kt) {
            f16x8 sh = *(const f16x8*)(&ws[l15][kt * 32 + lg4 * 8]);
            f16x8 wl0 = *(const f16x8*)(w2l_s + ((kt * 3 + 0) * 64 + l) * 8);
            f16x8 wl1 = *(const f16x8*)(w2l_s + ((kt * 3 + 1) * 64 + l) * 8);
            f16x8 wl2 = *(const f16x8*)(w2l_s + ((kt * 3 + 2) * 64 + l) * 8);
            a0 = __builtin_amdgcn_mfma_f32_16x16x32_f16(sh, W2h[kt * 3 + 0], a0, 0, 0, 0);
            a0 = __builtin_amdgcn_mfma_f32_16x16x32_f16(sh, wl0,             a0, 0, 0, 0);
            a1 = __builtin_amdgcn_mfma_f32_16x16x32_f16(sh, W2h[kt * 3 + 1], a1, 0, 0, 0);
            a1 = __builtin_amdgcn_mfma_f32_16x16x32_f16(sh, wl1,             a1, 0, 0, 0);
            a2 = __builtin_amdgcn_mfma_f32_16x16x32_f16(sh, W2h[kt * 3 + 2], a2, 0, 0, 0);
            a2 = __builtin_amdgcn_mfma_f32_16x16x32_f16(sh, wl2,             a2, 0, 0, 0);
        }
        float p0 = 0.f, p1 = 0.f, p2 = 0.f, p3 = 0.f;
        #pragma unroll
        for (int n = 0; n < 3; ++n) {
            f32x4 av = (n == 0) ? a0 : (n == 1) ? a1 : a2;
            p0 += wlr[n] * fast_sigmoid(av[0] + blr[n]);
            p1 += wlr[n] * fast_sigmoid(av[1] + blr[n]);
            p2 += wlr[n] * fast_sigmoid(av[2] + blr[n]);
            p3 += wlr[n] * fast_sigmoid(av[3] + blr[n]);
        }
        #pragma unroll
        for (int off = 1; off < 16; off <<= 1) {
            p0 += __shfl_xor(p0, off);
            p1 += __shfl_xor(p1, off);
            p2 += __shfl_xor(p2, off);
            p3 += __shfl_xor(p3, off);
        }
        if (l15 == 0) {
            int tb = m * 16 + lg4 * 4;
            lg[tb + 0] = p0; lg[tb + 1] = p1; lg[tb + 2] = p2; lg[tb + 3] = p3;
        }
    }

    // ---- per-wave masked softmax over t<200 (no barriers; wave-local lgt) ----
    const int* mrow = mask + (size_t)b * TT;
    const float NEG = -4294967295.0f;             // -2^32+1
    float v0 = lg[l];        if (mrow[l]        == 0) v0 = NEG;
    float v1 = lg[64 + l];   if (mrow[64 + l]   == 0) v1 = NEG;
    float v2 = lg[128 + l];  if (mrow[128 + l]  == 0) v2 = NEG;
    float v3 = -8589934590.0f;
    if (l < 8) { v3 = lg[192 + l]; if (mrow[192 + l] == 0) v3 = NEG; }

    float mx = fmaxf(fmaxf(v0, v1), fmaxf(v2, v3));
    #pragma unroll
    for (int off = 32; off; off >>= 1) mx = fmaxf(mx, __shfl_xor(mx, off));

    float e0 = __expf(v0 - mx), e1 = __expf(v1 - mx);
    float e2 = __expf(v2 - mx), e3 = __expf(v3 - mx);   // pad lanes underflow to 0
    float s = (e0 + e1) + (e2 + e3);
    #pragma unroll
    for (int off = 32; off; off >>= 1) s += __shfl_xor(s, off);

    float* orow = out + (size_t)b * TT;
    orow[l]       = e0 / s;
    orow[64 + l]  = e1 / s;
    orow[128 + l] = e2 / s;
    if (l < 8) orow[192 + l] = e3 / s;
}

extern "C" void kernel_launch(void* const* d_in, const int* in_sizes, int n_in,
                              void* d_out, int out_size, void* d_ws, size_t ws_size,
                              hipStream_t stream) {
    const float* q     = (const float*)d_in[0];
    const float* k     = (const float*)d_in[1];
    // d_in[2] = v : unused by the reference output
    const int*   mask  = (const int*)d_in[3];
    const float* Wq    = (const float*)d_in[4];
    const float* bq    = (const float*)d_in[5];
    const float* alpha = (const float*)d_in[6];
    const float* W1    = (const float*)d_in[7];
    const float* b1    = (const float*)d_in[8];
    const float* W2    = (const float*)d_in[9];
    const float* b2    = (const float*)d_in[10];
    const float* Wf    = (const float*)d_in[11];
    // d_in[12] = bf : dropped (softmax is shift-invariant, incl. all-masked rows)
    float* out = (float*)d_out;

    hipLaunchKernelGGL(pack_kernel, dim3((DD * H1 + 9 * 64 * 8 + 255) / 256), dim3(256),
                       0, stream, W1, W2);
    hipLaunchKernelGGL(din_mfma, dim3(BB / 4), dim3(256), 0, stream,
                       q, k, mask, Wq, bq, alpha, b1, b2, Wf, out);
}

// Round 4
// 53.669 us; speedup vs baseline: 1.8522x; 1.1575x over previous
//
#include <hip/hip_runtime.h>
#include <math.h>

typedef float f32x4 __attribute__((ext_vector_type(4)));
typedef _Float16 f16;
typedef f16 f16x8 __attribute__((ext_vector_type(8)));
typedef unsigned int u32;
typedef u32 u32x2 __attribute__((ext_vector_type(2)));

#define BB 4096
#define TT 200
#define DD 32
#define H1 80
#define H2 40
#define SLAB_W 104   // f16 per slab row: 96 used + 8 pad -> 208B stride, even bank spread

// packed tables (f32) + W2 hi fragment table (f16), coarse device globals
__device__ __align__(16) float g_BCj[DD * H1];   // (B-C)[k][j]
__device__ __align__(16) float g_Dj [DD * H1];   // D[k][j]
__device__ __align__(16) float g_ACj[DD * H1];   // (A+C)[k][j]
__device__ __align__(16) f16 g_w2h[9 * 64 * 8];  // [kt*3+n][lane][e]

__device__ __forceinline__ float fast_sigmoid(float x) {
    return __builtin_amdgcn_rcpf(1.f + __expf(-x));
}

__global__ void pack_kernel(const float* __restrict__ W1, const float* __restrict__ W2) {
    int idx = blockIdx.x * 256 + threadIdx.x;
    if (idx < DD * H1) {
        int kk = idx / H1, j = idx % H1;
        g_BCj[idx] = W1[(32 + kk) * H1 + j] - W1[(64 + kk) * H1 + j];
        g_Dj [idx] = W1[(96 + kk) * H1 + j];
        g_ACj[idx] = W1[kk * H1 + j] + W1[(64 + kk) * H1 + j];
        return;
    }
    idx -= DD * H1;
    if (idx < 9 * 64 * 8) {                       // W2 fragments (f16 hi), padded K=96 N=48
        int e = idx & 7, l = (idx >> 3) & 63, g = idx >> 9;
        int kt = g / 3, n = g % 3;
        int j   = kt * 32 + (l >> 4) * 8 + e;     // K index (H1 dim)
        int col = n * 16 + (l & 15);              // N index (H2 dim)
        float v = (j < H1 && col < H2) ? W2[j * H2 + col] : 0.f;
        g_w2h[idx] = (f16)v;
    }
}

// one batch-row per WAVE; waves fully independent; ZERO barriers
__global__ __launch_bounds__(256) void din_mfma(
    const float* __restrict__ q, const float* __restrict__ k, const int* __restrict__ mask,
    const float* __restrict__ Wq, const float* __restrict__ bq, const float* __restrict__ alpha,
    const float* __restrict__ b1, const float* __restrict__ b2, const float* __restrict__ Wf,
    float* __restrict__ out)
{
    const int tid = threadIdx.x;
    const int wid = tid >> 6, l = tid & 63;
    const int l15 = l & 15, lg4 = l >> 4;
    const int b   = (blockIdx.x << 2) | wid;      // this wave's batch row

    __shared__ __align__(16) f16   slab[4][16][SLAB_W];  // per-wave sg (f16 hi only)
    __shared__ __align__(16) float qp_s[4][DD];
    __shared__ __align__(16) float u_s[4][H1];
    __shared__ __align__(16) float lgt[4][208];

    // hoist mask row loads: HBM latency hides under the 13-tile main loop
    const int* mrow = mask + (size_t)b * TT;
    int mk0 = mrow[l];
    int mk1 = mrow[64 + l];
    int mk2 = mrow[128 + l];
    int mk3 = (l < 8) ? mrow[192 + l] : 1;

    // ---- phase 0a (per wave): qp = prelu(q[b] @ Wq + bq) ----
    if (l < DD) {
        const float* qr = q + (size_t)b * DD;
        float acc = bq[l];
        #pragma unroll
        for (int e = 0; e < DD; ++e) acc += qr[e] * Wq[e * DD + l];
        float a = alpha[l];
        qp_s[wid][l] = acc >= 0.f ? acc : a * acc;
    }
    // zero this wave's slab pad columns j=80..95 (kt=2 A-frag reads them; W2h=0 there,
    // but uninitialized LDS could hold NaN and NaN*0=NaN)
    {
        u32* wsz = (u32*)slab[wid];               // 52 u32 per row
        #pragma unroll
        for (int i = 0; i < 2; ++i) {
            int idx = i * 64 + l;                 // 0..127 = 16 rows x 8 u32
            wsz[(idx >> 3) * 52 + 40 + (idx & 7)] = 0u;
        }
    }

    // ---- phase 0b (per wave): u[j] = b1[j] + qp.(A+C)[:,j] ----
    #pragma unroll
    for (int i = 0; i < 2; ++i) {
        int c = i * 64 + l;
        if (c < H1) {
            float acc = b1[c];
            #pragma unroll
            for (int d = 0; d < DD; ++d) acc += qp_s[wid][d] * g_ACj[d * H1 + c];
            u_s[wid][c] = acc;
        }
    }
    // L1 A-operand frags (W1'): [j=n*16+l15][d=lg4*8+e], f16 hi/lo (keep B-lo guard)
    f16x8 Bh[5], Bl[5];
    #pragma unroll
    for (int n = 0; n < 5; ++n) {
        #pragma unroll
        for (int e = 0; e < 8; ++e) {
            int kidx = lg4 * 8 + e;
            int j = n * 16 + l15;
            float v = g_BCj[kidx * H1 + j] + qp_s[wid][kidx] * g_Dj[kidx * H1 + j];
            f16 hi = (f16)v;
            Bh[n][e] = hi;
            Bl[n][e] = (f16)(v - (float)hi);
        }
    }
    // W2 hi fragments in registers (lane-contiguous 16B loads)
    f16x8 W2h[9];
    #pragma unroll
    for (int g = 0; g < 9; ++g) W2h[g] = *(const f16x8*)(g_w2h + (g * 64 + l) * 8);
    // per-lane b2/Wf (col = n*16+l15)
    float blr[3], wlr[3];
    #pragma unroll
    for (int n = 0; n < 3; ++n) {
        int col = n * 16 + l15;
        blr[n] = col < H2 ? b2[col] : 0.f;
        wlr[n] = col < H2 ? Wf[col] : 0.f;
    }

    // ---- main loop: 13 m-tiles per wave, no barriers ----
    const float* kb = k + (size_t)b * (TT * DD);
    f16 (*ws)[SLAB_W] = slab[wid];
    float* lg = lgt[wid];

    f32x4 x0, x1;
    {
        const f32x4* kr = (const f32x4*)(kb + l15 * DD + lg4 * 8);
        x0 = kr[0]; x1 = kr[1];
    }

    for (int m = 0; m < 13; ++m) {
        // B-operand (k rows, col t=l15, k-slice lg4*8..+8), f16 hi only (A-lo dropped)
        f16x8 Ah;
        #pragma unroll
        for (int e = 0; e < 4; ++e) {
            Ah[e]     = (f16)x0[e];
            Ah[e + 4] = (f16)x1[e];
        }
        // prefetch next m-tile's k rows
        if (m < 12) {
            int tn = (m + 1) * 16 + l15; if (tn > TT - 1) tn = TT - 1;
            const f32x4* kr = (const f32x4*)(kb + tn * DD + lg4 * 8);
            x0 = kr[0]; x1 = kr[1];
        }

        // L1' (transposed): acc[r] = u[j0+r] + W1'[j0+r][:] . k[t=l15][:]
        #pragma unroll
        for (int n = 0; n < 5; ++n) {
            int j0 = n * 16 + lg4 * 4;
            f32x4 acc = *(const f32x4*)(&u_s[wid][j0]);   // bias folded into acc init
            acc = __builtin_amdgcn_mfma_f32_16x16x32_f16(Bh[n], Ah, acc, 0, 0, 0);
            acc = __builtin_amdgcn_mfma_f32_16x16x32_f16(Bl[n], Ah, acc, 0, 0, 0);
            auto p01 = __builtin_amdgcn_cvt_pkrtz(fast_sigmoid(acc[0]), fast_sigmoid(acc[1]));
            auto p23 = __builtin_amdgcn_cvt_pkrtz(fast_sigmoid(acc[2]), fast_sigmoid(acc[3]));
            u32x2 w;
            w[0] = __builtin_bit_cast(u32, p01);
            w[1] = __builtin_bit_cast(u32, p23);
            *(u32x2*)(&ws[l15][j0]) = w;
        }

        // L2: A = sg[t=l15][j-slice] from slab, B = W2h (regs only; W2-lo dropped)
        f32x4 a0 = {0.f,0.f,0.f,0.f}, a1 = {0.f,0.f,0.f,0.f}, a2 = {0.f,0.f,0.f,0.f};
        #pragma unroll
        for (int kt = 0; kt < 3; ++kt) {
            f16x8 sh = *(const f16x8*)(&ws[l15][kt * 32 + lg4 * 8]);
            a0 = __builtin_amdgcn_mfma_f32_16x16x32_f16(sh, W2h[kt * 3 + 0], a0, 0, 0, 0);
            a1 = __builtin_amdgcn_mfma_f32_16x16x32_f16(sh, W2h[kt * 3 + 1], a1, 0, 0, 0);
            a2 = __builtin_amdgcn_mfma_f32_16x16x32_f16(sh, W2h[kt * 3 + 2], a2, 0, 0, 0);
        }
        float p0 = 0.f, p1 = 0.f, p2 = 0.f, p3 = 0.f;
        #pragma unroll
        for (int n = 0; n < 3; ++n) {
            f32x4 av = (n == 0) ? a0 : (n == 1) ? a1 : a2;
            p0 += wlr[n] * fast_sigmoid(av[0] + blr[n]);
            p1 += wlr[n] * fast_sigmoid(av[1] + blr[n]);
            p2 += wlr[n] * fast_sigmoid(av[2] + blr[n]);
            p3 += wlr[n] * fast_sigmoid(av[3] + blr[n]);
        }
        #pragma unroll
        for (int off = 1; off < 16; off <<= 1) {
            p0 += __shfl_xor(p0, off);
            p1 += __shfl_xor(p1, off);
            p2 += __shfl_xor(p2, off);
            p3 += __shfl_xor(p3, off);
        }
        if (l15 == 0) {
            int tb = m * 16 + lg4 * 4;
            lg[tb + 0] = p0; lg[tb + 1] = p1; lg[tb + 2] = p2; lg[tb + 3] = p3;
        }
    }

    // ---- per-wave masked softmax over t<200 (wave-local lgt; mask preloaded) ----
    const float NEG = -4294967295.0f;             // -2^32+1
    float v0 = lg[l];        if (mk0 == 0) v0 = NEG;
    float v1 = lg[64 + l];   if (mk1 == 0) v1 = NEG;
    float v2 = lg[128 + l];  if (mk2 == 0) v2 = NEG;
    float v3 = -8589934590.0f;
    if (l < 8) { v3 = lg[192 + l]; if (mk3 == 0) v3 = NEG; }

    float mx = fmaxf(fmaxf(v0, v1), fmaxf(v2, v3));
    #pragma unroll
    for (int off = 32; off; off >>= 1) mx = fmaxf(mx, __shfl_xor(mx, off));

    float e0 = __expf(v0 - mx), e1 = __expf(v1 - mx);
    float e2 = __expf(v2 - mx), e3 = __expf(v3 - mx);   // pad lanes underflow to 0
    float s = (e0 + e1) + (e2 + e3);
    #pragma unroll
    for (int off = 32; off; off >>= 1) s += __shfl_xor(s, off);

    float* orow = out + (size_t)b * TT;
    orow[l]       = e0 / s;
    orow[64 + l]  = e1 / s;
    orow[128 + l] = e2 / s;
    if (l < 8) orow[192 + l] = e3 / s;
}

extern "C" void kernel_launch(void* const* d_in, const int* in_sizes, int n_in,
                              void* d_out, int out_size, void* d_ws, size_t ws_size,
                              hipStream_t stream) {
    const float* q     = (const float*)d_in[0];
    const float* k     = (const float*)d_in[1];
    // d_in[2] = v : unused by the reference output
    const int*   mask  = (const int*)d_in[3];
    const float* Wq    = (const float*)d_in[4];
    const float* bq    = (const float*)d_in[5];
    const float* alpha = (const float*)d_in[6];
    const float* W1    = (const float*)d_in[7];
    const float* b1    = (const float*)d_in[8];
    const float* W2    = (const float*)d_in[9];
    const float* b2    = (const float*)d_in[10];
    const float* Wf    = (const float*)d_in[11];
    // d_in[12] = bf : dropped (softmax is shift-invariant, incl. all-masked rows)
    float* out = (float*)d_out;

    hipLaunchKernelGGL(pack_kernel, dim3((DD * H1 + 9 * 64 * 8 + 255) / 256), dim3(256),
                       0, stream, W1, W2);
    hipLaunchKernelGGL(din_mfma, dim3(BB / 4), dim3(256), 0, stream,
                       q, k, mask, Wq, bq, alpha, b1, b2, Wf, out);
}